// Round 1
// baseline (106.603 us; speedup 1.0000x reference)
//
#include <hip/hip_runtime.h>
#include <hip/hip_bf16.h>
#include <stdint.h>

#define H 128
#define NU 100000
#define NI 50000

typedef __attribute__((ext_vector_type(8))) short short8;
typedef __attribute__((ext_vector_type(4))) float f32x4;

__device__ __forceinline__ float bf2f(uint32_t u) { return __uint_as_float(u << 16); }
__device__ __forceinline__ uint16_t f2bf(float f) {
    uint32_t x = __float_as_uint(f);
    return (uint16_t)((x + 0x7fffu + ((x >> 16) & 1u)) >> 16);  // RNE
}

// Swizzled byte offset into a [128][128] bf16 LDS tile (XOR bank swizzle,
// keeps 16B alignment: xor bits 4..6 only). 2-way conflict max on ds_read_b128.
__device__ __forceinline__ int lds_off(int row, int k) {
    return (row * 256 + k * 2) ^ ((row & 7) << 4);
}

// Computes Out[r][n] = bf16( sum_k Z[r][k] * W[k][n] )  for a 128-row block.
// Grid: first nub blocks -> users, rest -> items.
__global__ __launch_bounds__(256) void proj_kernel(
    const float* __restrict__ z_user, const float* __restrict__ z_item,
    const float* __restrict__ W1, uint16_t* __restrict__ U, uint16_t* __restrict__ Iout,
    int nub)
{
    __shared__ char lds[65536];
    char* Alds = lds;          // A tile: [128 rows][128 k] bf16, swizzled
    char* Blds = lds + 32768;  // B tile: [128 n][128 k] bf16 (W transposed), swizzled

    int bid = blockIdx.x;
    const float* Z; const float* W; uint16_t* Out; int M;
    if (bid < nub) { Z = z_user; W = W1;         Out = U;    M = NU; }
    else { bid -= nub; Z = z_item; W = W1 + H*H; Out = Iout; M = NI; }
    const int row0 = bid * 128;
    const int tid = threadIdx.x;

    // --- Stage A: z rows -> bf16 LDS (coalesced float4 loads) ---
    {
        int k4 = (tid & 31) * 4;   // 32 float4 per row of 128
        int r  = tid >> 5;         // 8 rows per pass
        #pragma unroll
        for (int p = 0; p < 16; ++p, r += 8) {
            int gr = row0 + r; if (gr >= M) gr = M - 1;  // clamp; stores guarded later
            f32x4 v = *(const f32x4*)(Z + (size_t)gr * H + k4);
            uint32_t lo = (uint32_t)f2bf(v.x) | ((uint32_t)f2bf(v.y) << 16);
            uint32_t hi = (uint32_t)f2bf(v.z) | ((uint32_t)f2bf(v.w) << 16);
            *(uint2*)(Alds + lds_off(r, k4)) = make_uint2(lo, hi);
        }
        // --- Stage B: W[k][n] -> Blds[n][k] (transpose into LDS, one-time) ---
        int n4 = (tid & 31) * 4;
        int k  = tid >> 5;
        #pragma unroll
        for (int p = 0; p < 16; ++p, k += 8) {
            f32x4 v = *(const f32x4*)(W + (size_t)k * H + n4);
            *(uint16_t*)(Blds + lds_off(n4 + 0, k)) = f2bf(v.x);
            *(uint16_t*)(Blds + lds_off(n4 + 1, k)) = f2bf(v.y);
            *(uint16_t*)(Blds + lds_off(n4 + 2, k)) = f2bf(v.z);
            *(uint16_t*)(Blds + lds_off(n4 + 3, k)) = f2bf(v.w);
        }
    }
    __syncthreads();

    const int w  = tid >> 6;       // wave 0..3 -> rows 32w..32w+31
    const int l  = tid & 63;
    const int lr = l & 15;         // fragment row (A) / col (B)
    const int lk = (l >> 4) * 8;   // k chunk base within 32

    f32x4 acc[2][8];
    #pragma unroll
    for (int m0 = 0; m0 < 2; ++m0)
        #pragma unroll
        for (int n0 = 0; n0 < 8; ++n0)
            acc[m0][n0] = (f32x4){0.f, 0.f, 0.f, 0.f};

    #pragma unroll
    for (int kk = 0; kk < 4; ++kk) {
        int kb = kk * 32 + lk;
        short8 a0 = *(const short8*)(Alds + lds_off(w*32 +      lr, kb));
        short8 a1 = *(const short8*)(Alds + lds_off(w*32 + 16 + lr, kb));
        #pragma unroll
        for (int n0 = 0; n0 < 8; ++n0) {
            short8 b = *(const short8*)(Blds + lds_off(n0*16 + lr, kb));
            acc[0][n0] = __builtin_amdgcn_mfma_f32_16x16x32_bf16(a0, b, acc[0][n0], 0, 0, 0);
            acc[1][n0] = __builtin_amdgcn_mfma_f32_16x16x32_bf16(a1, b, acc[1][n0], 0, 0, 0);
        }
    }

    // Epilogue: C/D layout col = lane&15, row = (lane>>4)*4 + ri  [m89-verified]
    const int rbase = row0 + w * 32;
    #pragma unroll
    for (int m0 = 0; m0 < 2; ++m0) {
        #pragma unroll
        for (int ri = 0; ri < 4; ++ri) {
            int gr = rbase + m0*16 + (l >> 4) * 4 + ri;
            if (gr < M) {
                #pragma unroll
                for (int n0 = 0; n0 < 8; ++n0)
                    Out[(size_t)gr * H + n0*16 + lr] = f2bf(acc[m0][n0][ri]);
            }
        }
    }
}

// out[e] = relu(U[row[e]] + I[col[e]] + b1) . W2 + b2
// 16 lanes per edge (8 bf16 each, one dwordx4 per array), 4 edges per wave.
__global__ __launch_bounds__(256) void edge_kernel(
    const uint16_t* __restrict__ U, const uint16_t* __restrict__ I,
    const int* __restrict__ row_idx, const int* __restrict__ col_idx,
    const float* __restrict__ b1, const float* __restrict__ W2,
    const float* __restrict__ b2p, float* __restrict__ out, int E)
{
    const int l = threadIdx.x & 63;
    const int g = l >> 4;
    const int t = l & 15;

    float b1v[8], w2v[8];
    #pragma unroll
    for (int j = 0; j < 8; ++j) { b1v[j] = b1[t*8 + j]; w2v[j] = W2[t*8 + j]; }
    const float b2 = *b2p;

    const int wid = (int)((blockIdx.x * blockDim.x + threadIdx.x) >> 6);
    const int nw  = (int)((gridDim.x * blockDim.x) >> 6);

    for (int e = wid * 4 + g; e < E; e += nw * 4) {
        int r = row_idx[e];
        int c = col_idx[e];
        uint4 uv = *(const uint4*)(U + (size_t)r * H + t * 8);
        uint4 iv = *(const uint4*)(I + (size_t)c * H + t * 8);
        const uint32_t* up = &uv.x;
        const uint32_t* ip = &iv.x;
        float acc = 0.f;
        #pragma unroll
        for (int j = 0; j < 4; ++j) {
            float h0 = bf2f(up[j] & 0xffffu) + bf2f(ip[j] & 0xffffu) + b1v[2*j];
            float h1 = bf2f(up[j] >> 16)     + bf2f(ip[j] >> 16)     + b1v[2*j+1];
            h0 = fmaxf(h0, 0.f);
            h1 = fmaxf(h1, 0.f);
            acc = fmaf(h0, w2v[2*j],   acc);
            acc = fmaf(h1, w2v[2*j+1], acc);
        }
        // reduce across the 16-lane group (xor masks stay inside the group)
        acc += __shfl_xor(acc, 8);
        acc += __shfl_xor(acc, 4);
        acc += __shfl_xor(acc, 2);
        acc += __shfl_xor(acc, 1);
        if (t == 0) out[e] = acc + b2;
    }
}

extern "C" void kernel_launch(void* const* d_in, const int* in_sizes, int n_in,
                              void* d_out, int out_size, void* d_ws, size_t ws_size,
                              hipStream_t stream) {
    const float* z_user = (const float*)d_in[0];
    const float* z_item = (const float*)d_in[1];
    const int*   row_idx = (const int*)d_in[2];
    const int*   col_idx = (const int*)d_in[3];
    const float* W1 = (const float*)d_in[4];
    const float* b1 = (const float*)d_in[5];
    const float* W2 = (const float*)d_in[6];
    const float* b2 = (const float*)d_in[7];
    float* out = (float*)d_out;
    const int E = in_sizes[2];

    uint16_t* U = (uint16_t*)d_ws;                  // 100000*128 bf16 = 25.6 MB
    uint16_t* I = U + (size_t)NU * H;               // 50000*128 bf16 = 12.8 MB

    const int nub = (NU + 127) / 128;  // 782
    const int nib = (NI + 127) / 128;  // 391
    proj_kernel<<<nub + nib, 256, 0, stream>>>(z_user, z_item, W1, U, I, nub);
    edge_kernel<<<2048, 256, 0, stream>>>(U, I, row_idx, col_idx, b1, W2, b2, out, E);
}

// Round 2
// 105.018 us; speedup vs baseline: 1.0151x; 1.0151x over previous
//
#include <hip/hip_runtime.h>
#include <hip/hip_bf16.h>
#include <stdint.h>

#define H 128
#define NU 100000
#define NI 50000

typedef __attribute__((ext_vector_type(8))) short short8;
typedef __attribute__((ext_vector_type(4))) float f32x4;

__device__ __forceinline__ float bf2f(uint32_t u) { return __uint_as_float(u << 16); }
__device__ __forceinline__ uint16_t f2bf(float f) {
    uint32_t x = __float_as_uint(f);
    return (uint16_t)((x + 0x7fffu + ((x >> 16) & 1u)) >> 16);  // RNE
}
__device__ __forceinline__ uint32_t cvtpk(float lo, float hi) {
    uint32_t r;
    asm("v_cvt_pk_bf16_f32 %0, %1, %2" : "=v"(r) : "v"(lo), "v"(hi));
    return r;
}

// Swizzled byte offset into a [128][128] bf16 LDS tile (XOR bank swizzle,
// keeps 16B alignment: xor bits 4..6 only).
__device__ __forceinline__ int lds_off(int row, int k) {
    return (row * 256 + k * 2) ^ ((row & 7) << 4);
}

// One-time: W1 [2H][H] f32 (k-major) -> Wt [2][H n][H k] bf16 (n-major).
__global__ __launch_bounds__(256) void wconv_kernel(
    const float* __restrict__ W1, uint16_t* __restrict__ Wt)
{
    __shared__ char lds[32768];
    const int half = blockIdx.x;
    const float* W = W1 + (size_t)half * H * H;
    uint16_t* Out = Wt + (size_t)half * H * H;
    const int tid = threadIdx.x;

    int n4 = (tid & 31) * 4;
    int k  = tid >> 5;
    #pragma unroll
    for (int p = 0; p < 16; ++p, k += 8) {
        f32x4 v = *(const f32x4*)(W + (size_t)k * H + n4);
        *(uint16_t*)(lds + lds_off(n4 + 0, k)) = f2bf(v.x);
        *(uint16_t*)(lds + lds_off(n4 + 1, k)) = f2bf(v.y);
        *(uint16_t*)(lds + lds_off(n4 + 2, k)) = f2bf(v.z);
        *(uint16_t*)(lds + lds_off(n4 + 3, k)) = f2bf(v.w);
    }
    __syncthreads();
    int n = tid >> 1;
    #pragma unroll
    for (int p = 0; p < 8; ++p) {
        int chunk = (tid & 1) * 8 + p;
        uint4 v = *(const uint4*)(lds + lds_off(n, chunk * 8));
        *(uint4*)(Out + (size_t)n * H + chunk * 8) = v;
    }
}

// Out[r][n] = bf16( sum_k Z[r][k] * W[k][n] + (item ? b1[n] : 0) )
// A fragments straight from global (f32 -> cvt_pk bf16); B from Wt via LDS.
__global__ __launch_bounds__(256) void proj_kernel(
    const float* __restrict__ z_user, const float* __restrict__ z_item,
    const uint16_t* __restrict__ Wt, const float* __restrict__ b1,
    uint16_t* __restrict__ U, uint16_t* __restrict__ Iout, int nub)
{
    __shared__ char lds[32768];

    int bid = blockIdx.x;
    const float* Z; const uint16_t* Wth; uint16_t* Out; int M; bool addb1;
    if (bid < nub) { Z = z_user; Wth = Wt;         Out = U;    M = NU; addb1 = false; }
    else { bid -= nub; Z = z_item; Wth = Wt + H*H; Out = Iout; M = NI; addb1 = true; }
    const int row0 = bid * 128;
    const int tid = threadIdx.x;

    // Stage B: Wt half (bf16 [n][k]) -> LDS, swizzled, vector all the way.
    {
        int n = tid >> 1;
        #pragma unroll
        for (int p = 0; p < 8; ++p) {
            int chunk = (tid & 1) * 8 + p;
            uint4 v = *(const uint4*)(Wth + (size_t)n * H + chunk * 8);
            *(uint4*)(lds + lds_off(n, chunk * 8)) = v;
        }
    }
    __syncthreads();

    const int w  = tid >> 6;       // wave 0..3 -> rows 32w..32w+31
    const int l  = tid & 63;
    const int lr = l & 15;
    const int lk = (l >> 4) * 8;

    int r0 = row0 + w * 32 + lr;
    int r1 = r0 + 16;
    const float* a0p = Z + (size_t)(r0 < M ? r0 : M - 1) * H;
    const float* a1p = Z + (size_t)(r1 < M ? r1 : M - 1) * H;

    f32x4 acc[2][8];
    #pragma unroll
    for (int m0 = 0; m0 < 2; ++m0)
        #pragma unroll
        for (int n0 = 0; n0 < 8; ++n0)
            acc[m0][n0] = (f32x4){0.f, 0.f, 0.f, 0.f};

    #pragma unroll
    for (int kk = 0; kk < 4; ++kk) {
        int kb = kk * 32 + lk;
        f32x4 v00 = *(const f32x4*)(a0p + kb);
        f32x4 v01 = *(const f32x4*)(a0p + kb + 4);
        f32x4 v10 = *(const f32x4*)(a1p + kb);
        f32x4 v11 = *(const f32x4*)(a1p + kb + 4);
        short8 a0, a1;
        uint32_t* A0 = (uint32_t*)&a0;
        uint32_t* A1 = (uint32_t*)&a1;
        A0[0] = cvtpk(v00.x, v00.y); A0[1] = cvtpk(v00.z, v00.w);
        A0[2] = cvtpk(v01.x, v01.y); A0[3] = cvtpk(v01.z, v01.w);
        A1[0] = cvtpk(v10.x, v10.y); A1[1] = cvtpk(v10.z, v10.w);
        A1[2] = cvtpk(v11.x, v11.y); A1[3] = cvtpk(v11.z, v11.w);
        #pragma unroll
        for (int n0 = 0; n0 < 8; ++n0) {
            short8 b = *(const short8*)(lds + lds_off(n0*16 + lr, kb));
            acc[0][n0] = __builtin_amdgcn_mfma_f32_16x16x32_bf16(a0, b, acc[0][n0], 0, 0, 0);
            acc[1][n0] = __builtin_amdgcn_mfma_f32_16x16x32_bf16(a1, b, acc[1][n0], 0, 0, 0);
        }
    }

    float b1v[8];
    #pragma unroll
    for (int n0 = 0; n0 < 8; ++n0) b1v[n0] = addb1 ? b1[n0*16 + lr] : 0.f;

    // C/D layout: col = lane&15, row = (lane>>4)*4 + ri  [m89-verified]
    const int rbase = row0 + w * 32;
    #pragma unroll
    for (int m0 = 0; m0 < 2; ++m0) {
        #pragma unroll
        for (int ri = 0; ri < 4; ++ri) {
            int gr = rbase + m0*16 + (l >> 4) * 4 + ri;
            if (gr < M) {
                #pragma unroll
                for (int n0 = 0; n0 < 8; ++n0)
                    Out[(size_t)gr * H + n0*16 + lr] = f2bf(acc[m0][n0][ri] + b1v[n0]);
            }
        }
    }
}

// out[e] = relu(U[row[e]] + I[col[e]]) . W2 + b2   (b1 pre-folded into I)
// 16 lanes per edge, 2 edges per group per iter -> 8 edges / wave-iter,
// 4 outstanding dwordx4 gathers per wave.
__device__ __forceinline__ float edge_dot(uint4 uv, uint4 iv, const float* w2v) {
    const uint32_t* up = &uv.x;
    const uint32_t* ip = &iv.x;
    float acc = 0.f;
    #pragma unroll
    for (int j = 0; j < 4; ++j) {
        float h0 = __uint_as_float(up[j] << 16) + __uint_as_float(ip[j] << 16);
        float h1 = __uint_as_float(up[j] & 0xffff0000u) + __uint_as_float(ip[j] & 0xffff0000u);
        acc = fmaf(fmaxf(h0, 0.f), w2v[2*j],   acc);
        acc = fmaf(fmaxf(h1, 0.f), w2v[2*j+1], acc);
    }
    return acc;
}

__global__ __launch_bounds__(256) void edge_kernel(
    const uint16_t* __restrict__ U, const uint16_t* __restrict__ I,
    const int* __restrict__ row_idx, const int* __restrict__ col_idx,
    const float* __restrict__ W2, const float* __restrict__ b2p,
    float* __restrict__ out, int E)
{
    const int l = threadIdx.x & 63;
    const int g = l >> 4;
    const int t = l & 15;

    float w2v[8];
    #pragma unroll
    for (int j = 0; j < 8; ++j) w2v[j] = W2[t*8 + j];
    const float b2 = *b2p;

    const int wid = (int)((blockIdx.x * blockDim.x + threadIdx.x) >> 6);
    const int nw  = (int)((gridDim.x * blockDim.x) >> 6);
    const int stride = nw * 8;

    for (int e0 = wid * 8 + g * 2; e0 + 1 < E; e0 += stride) {
        int2 rp = *(const int2*)(row_idx + e0);
        int2 cp = *(const int2*)(col_idx + e0);
        uint4 u0 = *(const uint4*)(U + (size_t)rp.x * H + t * 8);
        uint4 i0 = *(const uint4*)(I + (size_t)cp.x * H + t * 8);
        uint4 u1 = *(const uint4*)(U + (size_t)rp.y * H + t * 8);
        uint4 i1 = *(const uint4*)(I + (size_t)cp.y * H + t * 8);
        float acc0 = edge_dot(u0, i0, w2v);
        float acc1 = edge_dot(u1, i1, w2v);
        acc0 += __shfl_xor(acc0, 8);
        acc0 += __shfl_xor(acc0, 4);
        acc0 += __shfl_xor(acc0, 2);
        acc0 += __shfl_xor(acc0, 1);
        acc1 += __shfl_xor(acc1, 8);
        acc1 += __shfl_xor(acc1, 4);
        acc1 += __shfl_xor(acc1, 2);
        acc1 += __shfl_xor(acc1, 1);
        if (t == 0) {
            float2 o; o.x = acc0 + b2; o.y = acc1 + b2;
            *(float2*)(out + e0) = o;
        }
    }
    // odd-E tail (not hit for E = 1M, kept for safety)
    if ((E & 1) && (wid == 0) && (g == 0)) {
        int e = E - 1;
        int r = row_idx[e], c = col_idx[e];
        uint4 uv = *(const uint4*)(U + (size_t)r * H + t * 8);
        uint4 iv = *(const uint4*)(I + (size_t)c * H + t * 8);
        float acc = edge_dot(uv, iv, w2v);
        acc += __shfl_xor(acc, 8);
        acc += __shfl_xor(acc, 4);
        acc += __shfl_xor(acc, 2);
        acc += __shfl_xor(acc, 1);
        if (t == 0) out[e] = acc + b2;
    }
}

extern "C" void kernel_launch(void* const* d_in, const int* in_sizes, int n_in,
                              void* d_out, int out_size, void* d_ws, size_t ws_size,
                              hipStream_t stream) {
    const float* z_user = (const float*)d_in[0];
    const float* z_item = (const float*)d_in[1];
    const int*   row_idx = (const int*)d_in[2];
    const int*   col_idx = (const int*)d_in[3];
    const float* W1 = (const float*)d_in[4];
    const float* b1 = (const float*)d_in[5];
    const float* W2 = (const float*)d_in[6];
    const float* b2 = (const float*)d_in[7];
    float* out = (float*)d_out;
    const int E = in_sizes[2];

    uint16_t* U  = (uint16_t*)d_ws;                 // 100000*128 bf16 = 25.6 MB
    uint16_t* I  = U + (size_t)NU * H;              // 50000*128 bf16 = 12.8 MB
    uint16_t* Wt = I + (size_t)NI * H;              // 2*128*128 bf16 = 64 KB

    const int nub = (NU + 127) / 128;  // 782
    const int nib = (NI + 127) / 128;  // 391
    wconv_kernel<<<2, 256, 0, stream>>>(W1, Wt);
    proj_kernel<<<nub + nib, 256, 0, stream>>>(z_user, z_item, Wt, b1, U, I, nub);
    edge_kernel<<<2048, 256, 0, stream>>>(U, I, row_idx, col_idx, W2, b2, out, E);
}

// Round 3
// 100.454 us; speedup vs baseline: 1.0612x; 1.0454x over previous
//
#include <hip/hip_runtime.h>
#include <hip/hip_bf16.h>
#include <stdint.h>

#define H 128
#define NU 100000
#define NI 50000

typedef __attribute__((ext_vector_type(8))) short short8;
typedef __attribute__((ext_vector_type(4))) float f32x4;

__device__ __forceinline__ uint16_t f2bf(float f) {
    uint32_t x = __float_as_uint(f);
    return (uint16_t)((x + 0x7fffu + ((x >> 16) & 1u)) >> 16);  // RNE
}
__device__ __forceinline__ uint32_t cvtpk(float lo, float hi) {
    uint32_t r;
    asm("v_cvt_pk_bf16_f32 %0, %1, %2" : "=v"(r) : "v"(lo), "v"(hi));
    return r;
}

// Swizzled byte offset into a [128][128] bf16 LDS tile (XOR bank swizzle,
// keeps 16B alignment: xor bits 4..6 only).
__device__ __forceinline__ int lds_off(int row, int k) {
    return (row * 256 + k * 2) ^ ((row & 7) << 4);
}

// U/I are stored PERMUTED: element (r, c) lives at U'[r*128 + (c&15)*8 + (c>>4)].
// proj writes lane-contiguous MFMA fragments; edge reads lane t elems j=0..7
// as columns c = j*16 + t and indexes W2 accordingly.

// One-time: W1 [2H][H] f32 (k-major) -> Wt [2][H n][H k] bf16 (n-major).
__global__ __launch_bounds__(256) void wconv_kernel(
    const float* __restrict__ W1, uint16_t* __restrict__ Wt)
{
    __shared__ char lds[32768];
    const int half = blockIdx.x;
    const float* W = W1 + (size_t)half * H * H;
    uint16_t* Out = Wt + (size_t)half * H * H;
    const int tid = threadIdx.x;

    int n4 = (tid & 31) * 4;
    int k  = tid >> 5;
    #pragma unroll
    for (int p = 0; p < 16; ++p, k += 8) {
        f32x4 v = *(const f32x4*)(W + (size_t)k * H + n4);
        *(uint16_t*)(lds + lds_off(n4 + 0, k)) = f2bf(v.x);
        *(uint16_t*)(lds + lds_off(n4 + 1, k)) = f2bf(v.y);
        *(uint16_t*)(lds + lds_off(n4 + 2, k)) = f2bf(v.z);
        *(uint16_t*)(lds + lds_off(n4 + 3, k)) = f2bf(v.w);
    }
    __syncthreads();
    int n = tid >> 1;
    #pragma unroll
    for (int p = 0; p < 8; ++p) {
        int chunk = (tid & 1) * 8 + p;
        uint4 v = *(const uint4*)(lds + lds_off(n, chunk * 8));
        *(uint4*)(Out + (size_t)n * H + chunk * 8) = v;
    }
}

// Out'[r][perm(n)] = bf16( sum_k Z[r][k] * W[k][n] + (item ? b1[n] : 0) )
__global__ __launch_bounds__(256) void proj_kernel(
    const float* __restrict__ z_user, const float* __restrict__ z_item,
    const uint16_t* __restrict__ Wt, const float* __restrict__ b1,
    uint16_t* __restrict__ U, uint16_t* __restrict__ Iout, int nub)
{
    __shared__ char lds[32768];

    int bid = blockIdx.x;
    const float* Z; const uint16_t* Wth; uint16_t* Out; int M; bool addb1;
    if (bid < nub) { Z = z_user; Wth = Wt;         Out = U;    M = NU; addb1 = false; }
    else { bid -= nub; Z = z_item; Wth = Wt + H*H; Out = Iout; M = NI; addb1 = true; }
    const int row0 = bid * 128;
    const int tid = threadIdx.x;

    // Stage B: Wt half (bf16 [n][k]) -> LDS, swizzled, vector all the way.
    {
        int n = tid >> 1;
        #pragma unroll
        for (int p = 0; p < 8; ++p) {
            int chunk = (tid & 1) * 8 + p;
            uint4 v = *(const uint4*)(Wth + (size_t)n * H + chunk * 8);
            *(uint4*)(lds + lds_off(n, chunk * 8)) = v;
        }
    }
    __syncthreads();

    const int w  = tid >> 6;       // wave 0..3 -> rows 32w..32w+31
    const int l  = tid & 63;
    const int lr = l & 15;
    const int lk = (l >> 4) * 8;

    int r0 = row0 + w * 32 + lr;
    int r1 = r0 + 16;
    const float* a0p = Z + (size_t)(r0 < M ? r0 : M - 1) * H;
    const float* a1p = Z + (size_t)(r1 < M ? r1 : M - 1) * H;

    f32x4 acc[2][8];
    #pragma unroll
    for (int m0 = 0; m0 < 2; ++m0)
        #pragma unroll
        for (int n0 = 0; n0 < 8; ++n0)
            acc[m0][n0] = (f32x4){0.f, 0.f, 0.f, 0.f};

    #pragma unroll
    for (int kk = 0; kk < 4; ++kk) {
        int kb = kk * 32 + lk;
        f32x4 v00 = *(const f32x4*)(a0p + kb);
        f32x4 v01 = *(const f32x4*)(a0p + kb + 4);
        f32x4 v10 = *(const f32x4*)(a1p + kb);
        f32x4 v11 = *(const f32x4*)(a1p + kb + 4);
        short8 a0, a1;
        uint32_t* A0 = (uint32_t*)&a0;
        uint32_t* A1 = (uint32_t*)&a1;
        A0[0] = cvtpk(v00.x, v00.y); A0[1] = cvtpk(v00.z, v00.w);
        A0[2] = cvtpk(v01.x, v01.y); A0[3] = cvtpk(v01.z, v01.w);
        A1[0] = cvtpk(v10.x, v10.y); A1[1] = cvtpk(v10.z, v10.w);
        A1[2] = cvtpk(v11.x, v11.y); A1[3] = cvtpk(v11.z, v11.w);
        #pragma unroll
        for (int n0 = 0; n0 < 8; ++n0) {
            short8 b = *(const short8*)(lds + lds_off(n0*16 + lr, kb));
            acc[0][n0] = __builtin_amdgcn_mfma_f32_16x16x32_bf16(a0, b, acc[0][n0], 0, 0, 0);
            acc[1][n0] = __builtin_amdgcn_mfma_f32_16x16x32_bf16(a1, b, acc[1][n0], 0, 0, 0);
        }
    }

    float b1v[8];
    #pragma unroll
    for (int n0 = 0; n0 < 8; ++n0) b1v[n0] = addb1 ? b1[n0*16 + lr] : 0.f;

    // C/D layout: col = lane&15, row = (lane>>4)*4 + ri.  Permuted store:
    // lane lr owns cols {n0*16+lr} -> contiguous 16B at elem offset lr*8.
    const int rbase = row0 + w * 32;
    #pragma unroll
    for (int m0 = 0; m0 < 2; ++m0) {
        #pragma unroll
        for (int ri = 0; ri < 4; ++ri) {
            int gr = rbase + m0*16 + (l >> 4) * 4 + ri;
            if (gr < M) {
                uint4 pk;
                pk.x = cvtpk(acc[m0][0][ri] + b1v[0], acc[m0][1][ri] + b1v[1]);
                pk.y = cvtpk(acc[m0][2][ri] + b1v[2], acc[m0][3][ri] + b1v[3]);
                pk.z = cvtpk(acc[m0][4][ri] + b1v[4], acc[m0][5][ri] + b1v[5]);
                pk.w = cvtpk(acc[m0][6][ri] + b1v[6], acc[m0][7][ri] + b1v[7]);
                *(uint4*)(Out + (size_t)gr * H + lr * 8) = pk;
            }
        }
    }
}

// out[e] = relu(U[row[e]] + I[col[e]]) . W2 + b2   (b1 pre-folded into I;
// U/I in permuted layout: lane t elem j is column j*16+t).
__device__ __forceinline__ float edge_dot(uint4 uv, uint4 iv, const float* w2v) {
    const uint32_t* up = &uv.x;
    const uint32_t* ip = &iv.x;
    float acc = 0.f;
    #pragma unroll
    for (int j = 0; j < 4; ++j) {
        float h0 = __uint_as_float(up[j] << 16) + __uint_as_float(ip[j] << 16);
        float h1 = __uint_as_float(up[j] & 0xffff0000u) + __uint_as_float(ip[j] & 0xffff0000u);
        acc = fmaf(fmaxf(h0, 0.f), w2v[2*j],   acc);
        acc = fmaf(fmaxf(h1, 0.f), w2v[2*j+1], acc);
    }
    return acc;
}

__device__ __forceinline__ float group_reduce(float acc) {
    acc += __shfl_xor(acc, 8);
    acc += __shfl_xor(acc, 4);
    acc += __shfl_xor(acc, 2);
    acc += __shfl_xor(acc, 1);
    return acc;
}

__global__ __launch_bounds__(256) void edge_kernel(
    const uint16_t* __restrict__ U, const uint16_t* __restrict__ I,
    const int* __restrict__ row_idx, const int* __restrict__ col_idx,
    const float* __restrict__ W2, const float* __restrict__ b2p,
    float* __restrict__ out, int E)
{
    const int l = threadIdx.x & 63;
    const int g = l >> 4;
    const int t = l & 15;

    float w2v[8];
    #pragma unroll
    for (int j = 0; j < 8; ++j) w2v[j] = W2[j * 16 + t];  // permuted layout
    const float b2 = *b2p;

    const int wid = (int)((blockIdx.x * blockDim.x + threadIdx.x) >> 6);
    const int nw  = (int)((gridDim.x * blockDim.x) >> 6);
    const int stride = nw * 16;
    const int Emain = E & ~3;

    for (int e0 = wid * 16 + g * 4; e0 + 3 < E; e0 += stride) {
        int4 rp = *(const int4*)(row_idx + e0);
        int4 cp = *(const int4*)(col_idx + e0);
        uint4 u0 = *(const uint4*)(U + (size_t)rp.x * H + t * 8);
        uint4 i0 = *(const uint4*)(I + (size_t)cp.x * H + t * 8);
        uint4 u1 = *(const uint4*)(U + (size_t)rp.y * H + t * 8);
        uint4 i1 = *(const uint4*)(I + (size_t)cp.y * H + t * 8);
        uint4 u2 = *(const uint4*)(U + (size_t)rp.z * H + t * 8);
        uint4 i2 = *(const uint4*)(I + (size_t)cp.z * H + t * 8);
        uint4 u3 = *(const uint4*)(U + (size_t)rp.w * H + t * 8);
        uint4 i3 = *(const uint4*)(I + (size_t)cp.w * H + t * 8);
        float a0 = group_reduce(edge_dot(u0, i0, w2v));
        float a1 = group_reduce(edge_dot(u1, i1, w2v));
        float a2 = group_reduce(edge_dot(u2, i2, w2v));
        float a3 = group_reduce(edge_dot(u3, i3, w2v));
        if (t == 0) {
            f32x4 o; o.x = a0 + b2; o.y = a1 + b2; o.z = a2 + b2; o.w = a3 + b2;
            *(f32x4*)(out + e0) = o;
        }
    }
    // tail (E % 4 != 0) — not hit for E = 1M
    if (wid == 0 && g == 0) {
        for (int e = Emain; e < E; ++e) {
            int r = row_idx[e], c = col_idx[e];
            uint4 uv = *(const uint4*)(U + (size_t)r * H + t * 8);
            uint4 iv = *(const uint4*)(I + (size_t)c * H + t * 8);
            float acc = group_reduce(edge_dot(uv, iv, w2v));
            if (t == 0) out[e] = acc + b2;
        }
    }
}

extern "C" void kernel_launch(void* const* d_in, const int* in_sizes, int n_in,
                              void* d_out, int out_size, void* d_ws, size_t ws_size,
                              hipStream_t stream) {
    const float* z_user = (const float*)d_in[0];
    const float* z_item = (const float*)d_in[1];
    const int*   row_idx = (const int*)d_in[2];
    const int*   col_idx = (const int*)d_in[3];
    const float* W1 = (const float*)d_in[4];
    const float* b1 = (const float*)d_in[5];
    const float* W2 = (const float*)d_in[6];
    const float* b2 = (const float*)d_in[7];
    float* out = (float*)d_out;
    const int E = in_sizes[2];

    uint16_t* U  = (uint16_t*)d_ws;                 // 100000*128 bf16 = 25.6 MB
    uint16_t* I  = U + (size_t)NU * H;              // 50000*128 bf16 = 12.8 MB
    uint16_t* Wt = I + (size_t)NI * H;              // 2*128*128 bf16 = 64 KB

    const int nub = (NU + 127) / 128;  // 782
    const int nib = (NI + 127) / 128;  // 391
    wconv_kernel<<<2, 256, 0, stream>>>(W1, Wt);
    proj_kernel<<<nub + nib, 256, 0, stream>>>(z_user, z_item, Wt, b1, U, I, nub);
    edge_kernel<<<2048, 256, 0, stream>>>(U, I, row_idx, col_idx, W2, b2, out, E);
}

// Round 4
// 71.885 us; speedup vs baseline: 1.4830x; 1.3974x over previous
//
#include <hip/hip_runtime.h>
#include <hip/hip_bf16.h>
#include <stdint.h>

#define H 128
#define NU 100000
#define NI 50000

typedef __attribute__((ext_vector_type(8))) short short8;
typedef __attribute__((ext_vector_type(4))) float f32x4;

__device__ __forceinline__ uint16_t f2bf(float f) {
    uint32_t x = __float_as_uint(f);
    return (uint16_t)((x + 0x7fffu + ((x >> 16) & 1u)) >> 16);  // RNE
}
__device__ __forceinline__ uint32_t cvtpk(float lo, float hi) {
    uint32_t r;
    asm("v_cvt_pk_bf16_f32 %0, %1, %2" : "=v"(r) : "v"(lo), "v"(hi));
    return r;
}
__device__ __forceinline__ float cvt_ub0(uint32_t v) { float f; asm("v_cvt_f32_ubyte0 %0, %1" : "=v"(f) : "v"(v)); return f; }
__device__ __forceinline__ float cvt_ub1(uint32_t v) { float f; asm("v_cvt_f32_ubyte1 %0, %1" : "=v"(f) : "v"(v)); return f; }
__device__ __forceinline__ float cvt_ub2(uint32_t v) { float f; asm("v_cvt_f32_ubyte2 %0, %1" : "=v"(f) : "v"(v)); return f; }
__device__ __forceinline__ float cvt_ub3(uint32_t v) { float f; asm("v_cvt_f32_ubyte3 %0, %1" : "=v"(f) : "v"(v)); return f; }

// Swizzled byte offset into a [128][128] bf16 LDS tile (XOR bank swizzle).
__device__ __forceinline__ int lds_off(int row, int k) {
    return (row * 256 + k * 2) ^ ((row & 7) << 4);
}

// Tables are per-row-scaled biased int8, PERMUTED columns: byte position
// p = lr*8 + n0 holds column n0*16 + lr.  value = scale * (q - 128).
// Edge lane t reads bytes [t*8, t*8+8) = columns {j*16+t}, j=0..7.

// One-time: W1 [2H][H] f32 (k-major) -> Wt [2][H n][H k] bf16 (n-major).
__global__ __launch_bounds__(256) void wconv_kernel(
    const float* __restrict__ W1, uint16_t* __restrict__ Wt)
{
    __shared__ char lds[32768];
    const int half = blockIdx.x;
    const float* W = W1 + (size_t)half * H * H;
    uint16_t* Out = Wt + (size_t)half * H * H;
    const int tid = threadIdx.x;

    int n4 = (tid & 31) * 4;
    int k  = tid >> 5;
    #pragma unroll
    for (int p = 0; p < 16; ++p, k += 8) {
        f32x4 v = *(const f32x4*)(W + (size_t)k * H + n4);
        *(uint16_t*)(lds + lds_off(n4 + 0, k)) = f2bf(v.x);
        *(uint16_t*)(lds + lds_off(n4 + 1, k)) = f2bf(v.y);
        *(uint16_t*)(lds + lds_off(n4 + 2, k)) = f2bf(v.z);
        *(uint16_t*)(lds + lds_off(n4 + 3, k)) = f2bf(v.w);
    }
    __syncthreads();
    int n = tid >> 1;
    #pragma unroll
    for (int p = 0; p < 8; ++p) {
        int chunk = (tid & 1) * 8 + p;
        uint4 v = *(const uint4*)(lds + lds_off(n, chunk * 8));
        *(uint4*)(Out + (size_t)n * H + chunk * 8) = v;
    }
}

// Project 128 rows, quantize each output row to int8 with per-row scale.
__global__ __launch_bounds__(256) void proj_kernel(
    const float* __restrict__ z_user, const float* __restrict__ z_item,
    const uint16_t* __restrict__ Wt, const float* __restrict__ b1,
    uint8_t* __restrict__ U8, uint8_t* __restrict__ I8,
    float* __restrict__ Us, float* __restrict__ Is, int nub)
{
    __shared__ char lds[32768];

    int bid = blockIdx.x;
    const float* Z; const uint16_t* Wth; uint8_t* Out8; float* Sc; int M; bool addb1;
    if (bid < nub) { Z = z_user; Wth = Wt;         Out8 = U8; Sc = Us; M = NU; addb1 = false; }
    else { bid -= nub; Z = z_item; Wth = Wt + H*H; Out8 = I8; Sc = Is; M = NI; addb1 = true; }
    const int row0 = bid * 128;
    const int tid = threadIdx.x;

    // Stage B: Wt half (bf16 [n][k]) -> LDS, swizzled, vector all the way.
    {
        int n = tid >> 1;
        #pragma unroll
        for (int p = 0; p < 8; ++p) {
            int chunk = (tid & 1) * 8 + p;
            uint4 v = *(const uint4*)(Wth + (size_t)n * H + chunk * 8);
            *(uint4*)(lds + lds_off(n, chunk * 8)) = v;
        }
    }
    __syncthreads();

    const int w  = tid >> 6;       // wave 0..3 -> rows 32w..32w+31
    const int l  = tid & 63;
    const int lr = l & 15;
    const int lk = (l >> 4) * 8;

    int r0 = row0 + w * 32 + lr;
    int r1 = r0 + 16;
    const float* a0p = Z + (size_t)(r0 < M ? r0 : M - 1) * H;
    const float* a1p = Z + (size_t)(r1 < M ? r1 : M - 1) * H;

    f32x4 acc[2][8];
    #pragma unroll
    for (int m0 = 0; m0 < 2; ++m0)
        #pragma unroll
        for (int n0 = 0; n0 < 8; ++n0)
            acc[m0][n0] = (f32x4){0.f, 0.f, 0.f, 0.f};

    #pragma unroll
    for (int kk = 0; kk < 4; ++kk) {
        int kb = kk * 32 + lk;
        f32x4 v00 = *(const f32x4*)(a0p + kb);
        f32x4 v01 = *(const f32x4*)(a0p + kb + 4);
        f32x4 v10 = *(const f32x4*)(a1p + kb);
        f32x4 v11 = *(const f32x4*)(a1p + kb + 4);
        short8 a0, a1;
        uint32_t* A0 = (uint32_t*)&a0;
        uint32_t* A1 = (uint32_t*)&a1;
        A0[0] = cvtpk(v00.x, v00.y); A0[1] = cvtpk(v00.z, v00.w);
        A0[2] = cvtpk(v01.x, v01.y); A0[3] = cvtpk(v01.z, v01.w);
        A1[0] = cvtpk(v10.x, v10.y); A1[1] = cvtpk(v10.z, v10.w);
        A1[2] = cvtpk(v11.x, v11.y); A1[3] = cvtpk(v11.z, v11.w);
        #pragma unroll
        for (int n0 = 0; n0 < 8; ++n0) {
            short8 b = *(const short8*)(lds + lds_off(n0*16 + lr, kb));
            acc[0][n0] = __builtin_amdgcn_mfma_f32_16x16x32_bf16(a0, b, acc[0][n0], 0, 0, 0);
            acc[1][n0] = __builtin_amdgcn_mfma_f32_16x16x32_bf16(a1, b, acc[1][n0], 0, 0, 0);
        }
    }

    float b1v[8];
    #pragma unroll
    for (int n0 = 0; n0 < 8; ++n0) b1v[n0] = addb1 ? b1[n0*16 + lr] : 0.f;

    // Quantizing epilogue. C/D layout: col = lane&15, row = (lane>>4)*4 + ri.
    // Row gr's 128 cols live on the 16 contiguous lanes q*16..q*16+15 (q=l>>4),
    // so shfl_xor 1/2/4/8 reduces the row max within the right lane set.
    const int rbase = row0 + w * 32;
    #pragma unroll
    for (int m0 = 0; m0 < 2; ++m0) {
        #pragma unroll
        for (int ri = 0; ri < 4; ++ri) {
            int gr = rbase + m0*16 + (l >> 4) * 4 + ri;
            float v[8];
            float am = 0.f;
            #pragma unroll
            for (int n0 = 0; n0 < 8; ++n0) {
                v[n0] = acc[m0][n0][ri] + b1v[n0];
                am = fmaxf(am, fabsf(v[n0]));
            }
            am = fmaxf(am, __shfl_xor(am, 1));
            am = fmaxf(am, __shfl_xor(am, 2));
            am = fmaxf(am, __shfl_xor(am, 4));
            am = fmaxf(am, __shfl_xor(am, 8));
            float s = am * (1.0f / 127.0f);
            float r = 127.0f / fmaxf(am, 1e-30f);
            uint32_t lo = 0, hi = 0;
            #pragma unroll
            for (int n0 = 0; n0 < 4; ++n0) {
                uint32_t q8 = (uint32_t)fmaf(v[n0], r, 128.5f);      // 1..255
                lo |= q8 << (8 * n0);
            }
            #pragma unroll
            for (int n0 = 4; n0 < 8; ++n0) {
                uint32_t q8 = (uint32_t)fmaf(v[n0], r, 128.5f);
                hi |= q8 << (8 * (n0 - 4));
            }
            if (gr < M) {
                *(uint2*)(Out8 + (size_t)gr * H + lr * 8) = make_uint2(lo, hi);
                if (lr == 0) Sc[gr] = s;
            }
        }
    }
}

// out[e] = relu(su*(qU-128) + si*(qI-128)) . W2 + b2   (b1 pre-folded into I)
__device__ __forceinline__ float edge_dot8(uint2 u, uint2 i, float su, float si,
                                           const float* w2v) {
    float k = -128.0f * (su + si);
    float acc = 0.f, h;
    h = fmaf(su, cvt_ub0(u.x), fmaf(si, cvt_ub0(i.x), k)); acc = fmaf(fmaxf(h, 0.f), w2v[0], acc);
    h = fmaf(su, cvt_ub1(u.x), fmaf(si, cvt_ub1(i.x), k)); acc = fmaf(fmaxf(h, 0.f), w2v[1], acc);
    h = fmaf(su, cvt_ub2(u.x), fmaf(si, cvt_ub2(i.x), k)); acc = fmaf(fmaxf(h, 0.f), w2v[2], acc);
    h = fmaf(su, cvt_ub3(u.x), fmaf(si, cvt_ub3(i.x), k)); acc = fmaf(fmaxf(h, 0.f), w2v[3], acc);
    h = fmaf(su, cvt_ub0(u.y), fmaf(si, cvt_ub0(i.y), k)); acc = fmaf(fmaxf(h, 0.f), w2v[4], acc);
    h = fmaf(su, cvt_ub1(u.y), fmaf(si, cvt_ub1(i.y), k)); acc = fmaf(fmaxf(h, 0.f), w2v[5], acc);
    h = fmaf(su, cvt_ub2(u.y), fmaf(si, cvt_ub2(i.y), k)); acc = fmaf(fmaxf(h, 0.f), w2v[6], acc);
    h = fmaf(su, cvt_ub3(u.y), fmaf(si, cvt_ub3(i.y), k)); acc = fmaf(fmaxf(h, 0.f), w2v[7], acc);
    return acc;
}

__device__ __forceinline__ float group_reduce(float acc) {
    acc += __shfl_xor(acc, 8);
    acc += __shfl_xor(acc, 4);
    acc += __shfl_xor(acc, 2);
    acc += __shfl_xor(acc, 1);
    return acc;
}

__global__ __launch_bounds__(256) void edge_kernel(
    const uint8_t* __restrict__ U8, const uint8_t* __restrict__ I8,
    const float* __restrict__ Us, const float* __restrict__ Is,
    const int* __restrict__ row_idx, const int* __restrict__ col_idx,
    const float* __restrict__ W2, const float* __restrict__ b2p,
    float* __restrict__ out, int E)
{
    const int l = threadIdx.x & 63;
    const int g = l >> 4;
    const int t = l & 15;

    float w2v[8];
    #pragma unroll
    for (int j = 0; j < 8; ++j) w2v[j] = W2[j * 16 + t];  // permuted layout
    const float b2 = *b2p;

    const int wid = (int)((blockIdx.x * blockDim.x + threadIdx.x) >> 6);
    const int nw  = (int)((gridDim.x * blockDim.x) >> 6);
    const int stride = nw * 16;
    const int Emain = E & ~3;

    for (int e0 = wid * 16 + g * 4; e0 + 3 < E; e0 += stride) {
        int4 rp = *(const int4*)(row_idx + e0);
        int4 cp = *(const int4*)(col_idx + e0);
        uint2 u0 = *(const uint2*)(U8 + (size_t)rp.x * H + t * 8);
        uint2 i0 = *(const uint2*)(I8 + (size_t)cp.x * H + t * 8);
        uint2 u1 = *(const uint2*)(U8 + (size_t)rp.y * H + t * 8);
        uint2 i1 = *(const uint2*)(I8 + (size_t)cp.y * H + t * 8);
        uint2 u2 = *(const uint2*)(U8 + (size_t)rp.z * H + t * 8);
        uint2 i2 = *(const uint2*)(I8 + (size_t)cp.z * H + t * 8);
        uint2 u3 = *(const uint2*)(U8 + (size_t)rp.w * H + t * 8);
        uint2 i3 = *(const uint2*)(I8 + (size_t)cp.w * H + t * 8);
        float su0 = Us[rp.x], si0 = Is[cp.x];
        float su1 = Us[rp.y], si1 = Is[cp.y];
        float su2 = Us[rp.z], si2 = Is[cp.z];
        float su3 = Us[rp.w], si3 = Is[cp.w];
        float a0 = group_reduce(edge_dot8(u0, i0, su0, si0, w2v));
        float a1 = group_reduce(edge_dot8(u1, i1, su1, si1, w2v));
        float a2 = group_reduce(edge_dot8(u2, i2, su2, si2, w2v));
        float a3 = group_reduce(edge_dot8(u3, i3, su3, si3, w2v));
        if (t == 0) {
            f32x4 o; o.x = a0 + b2; o.y = a1 + b2; o.z = a2 + b2; o.w = a3 + b2;
            *(f32x4*)(out + e0) = o;
        }
    }
    // tail (E % 4 != 0) — not hit for E = 1M
    if (wid == 0 && g == 0) {
        for (int e = Emain; e < E; ++e) {
            int r = row_idx[e], c = col_idx[e];
            uint2 uv = *(const uint2*)(U8 + (size_t)r * H + t * 8);
            uint2 iv = *(const uint2*)(I8 + (size_t)c * H + t * 8);
            float acc = group_reduce(edge_dot8(uv, iv, Us[r], Is[c], w2v));
            if (t == 0) out[e] = acc + b2;
        }
    }
}

extern "C" void kernel_launch(void* const* d_in, const int* in_sizes, int n_in,
                              void* d_out, int out_size, void* d_ws, size_t ws_size,
                              hipStream_t stream) {
    const float* z_user = (const float*)d_in[0];
    const float* z_item = (const float*)d_in[1];
    const int*   row_idx = (const int*)d_in[2];
    const int*   col_idx = (const int*)d_in[3];
    const float* W1 = (const float*)d_in[4];
    const float* b1 = (const float*)d_in[5];
    const float* W2 = (const float*)d_in[6];
    const float* b2 = (const float*)d_in[7];
    float* out = (float*)d_out;
    const int E = in_sizes[2];

    uint8_t* U8 = (uint8_t*)d_ws;                   // 100000*128 = 12.8 MB
    uint8_t* I8 = U8 + (size_t)NU * H;              // 50000*128  =  6.4 MB
    float*   Us = (float*)(I8 + (size_t)NI * H);    // 400 KB
    float*   Is = Us + NU;                          // 200 KB
    uint16_t* Wt = (uint16_t*)(Is + NI);            // 64 KB (16B-aligned)

    const int nub = (NU + 127) / 128;  // 782
    const int nib = (NI + 127) / 128;  // 391
    wconv_kernel<<<2, 256, 0, stream>>>(W1, Wt);
    proj_kernel<<<nub + nib, 256, 0, stream>>>(z_user, z_item, Wt, b1, U8, I8, Us, Is, nub);
    edge_kernel<<<2048, 256, 0, stream>>>(U8, I8, Us, Is, row_idx, col_idx, W2, b2, out, E);
}